// Round 2
// baseline (8284.552 us; speedup 1.0000x reference)
//
#include <hip/hip_runtime.h>

// Problem: soft product quantizer.
// z: (8,384,32,32) f32, C: (2048,384) f32, it unused.
// N=8192 points (n = b*1024 + h*32 + w), K=8 subspaces, d=48, M=2048 codes.
// logits[n,k,m] = 2*<x_nk, c_mk> - ||c_mk||^2  (softmax-equivalent to -dist)
// soft = softmax(logits, m); Zq = soft @ C_k; JSD between rows n and n+4096.
// Output: 3145728 f32 (z_quantized, NCHW) + 1 f32 (jsd scalar).

#define Z_BCH  (384 * 1024)
#define JSD_IDX 3145728

#define RED4(v)                                   \
    v.x += __shfl_xor(v.x, off);                  \
    v.y += __shfl_xor(v.y, off);                  \
    v.z += __shfl_xor(v.z, off);                  \
    v.w += __shfl_xor(v.w, off);

__global__ __launch_bounds__(256, 2)
void pq_fused(const float* __restrict__ Zin, const float* __restrict__ Cb,
              float* __restrict__ Out)
{
    const int tid  = threadIdx.x;
    const int lane = tid & 63;
    const int wv   = tid >> 6;           // wave 0..3, one (pair) per wave
    const int pb   = blockIdx.x & 1023;  // 1024 pair-blocks (4 pairs each)
    const int k    = blockIdx.x >> 10;   // subspace 0..7
    const int r0   = pb << 2;            // first p-row of this block

    // C tile transposed: CtT[c4][m] (c4 = d/4). Row stride 129 f4 -> staging
    // writes land on distinct bank groups; compute reads are lane-consecutive
    // 16B (conflict-free ds_read_b128).
    __shared__ float4 CtT[12][129];
    __shared__ float  c2t[128];
    __shared__ float4 xs4[8][12];  // 8 rows (4 p + 4 q) x 48 floats
    __shared__ float4 zq4[8][12];  // reduced Zq rows for the final store

    // ---- stage x rows (384 items, 256 threads -> strided loop!) ----
    for (int i = tid; i < 384; i += 256) {
        int row = i / 48;
        int c   = i - row * 48;
        int n   = r0 + (row & 3) + ((row & 4) ? 4096 : 0);
        int b   = n >> 10, pos = n & 1023;
        ((float*)xs4)[row * 48 + c] = Zin[b * Z_BCH + (k * 48 + c) * 1024 + pos];
    }
    __syncthreads();

    // x for this wave's pair -> registers (96 VGPR), frees LDS bandwidth.
    float4 xp[12], xq[12];
#pragma unroll
    for (int c4 = 0; c4 < 12; ++c4) { xp[c4] = xs4[wv][c4]; xq[c4] = xs4[4 + wv][c4]; }

    // Full logits in registers: m = j*64 + lane.
    float lp[32], lq[32];
    const float4* Cg4 = (const float4*)Cb;  // C row = 96 float4

    // =============== GEMM1: logits ===============
#pragma unroll
    for (int t = 0; t < 16; ++t) {
        __syncthreads();
#pragma unroll
        for (int i = 0; i < 6; ++i) {
            int idx = tid + i * 256;           // 1536 float4 per tile
            int mm  = idx / 12;
            int c4  = idx - mm * 12;
            CtT[c4][mm] = Cg4[(t * 128 + mm) * 96 + k * 12 + c4];
        }
        __syncthreads();
        if (tid < 128) {                        // ||c_mk||^2 for this tile
            float s = 0.f;
#pragma unroll
            for (int c4 = 0; c4 < 12; ++c4) {
                float4 v = CtT[c4][tid];
                s += v.x * v.x + v.y * v.y + v.z * v.z + v.w * v.w;
            }
            c2t[tid] = s;
        }
        __syncthreads();
#pragma unroll
        for (int jj = 0; jj < 2; ++jj) {
            int   mloc = (jj << 6) + lane;
            float ap = 0.f, aq = 0.f;
#pragma unroll
            for (int c4 = 0; c4 < 12; ++c4) {
                float4 cv = CtT[c4][mloc];
                ap += cv.x * xp[c4].x; ap += cv.y * xp[c4].y;
                ap += cv.z * xp[c4].z; ap += cv.w * xp[c4].w;
                aq += cv.x * xq[c4].x; aq += cv.y * xq[c4].y;
                aq += cv.z * xq[c4].z; aq += cv.w * xq[c4].w;
            }
            float cc = c2t[mloc];
            lp[t * 2 + jj] = 2.f * ap - cc;
            lq[t * 2 + jj] = 2.f * aq - cc;
        }
    }

    // =============== softmax (exact, in-wave) ===============
    float Mp = lp[0], Mq = lq[0];
#pragma unroll
    for (int j = 1; j < 32; ++j) { Mp = fmaxf(Mp, lp[j]); Mq = fmaxf(Mq, lq[j]); }
#pragma unroll
    for (int off = 32; off; off >>= 1) {
        Mp = fmaxf(Mp, __shfl_xor(Mp, off));
        Mq = fmaxf(Mq, __shfl_xor(Mq, off));
    }
    float Zp = 0.f, Zq = 0.f, Tp = 0.f, Tq = 0.f;
#pragma unroll
    for (int j = 0; j < 32; ++j) {
        float sp = lp[j] - Mp, sq = lq[j] - Mq;
        float ep = __expf(sp), eq = __expf(sq);
        Zp += ep; Zq += eq;
        Tp += ep * sp; Tq += eq * sq;   // for sum(p*log p) = T/Z - log Z
        lp[j] = ep; lq[j] = eq;
    }
#pragma unroll
    for (int off = 32; off; off >>= 1) {
        Zp += __shfl_xor(Zp, off); Zq += __shfl_xor(Zq, off);
        Tp += __shfl_xor(Tp, off); Tq += __shfl_xor(Tq, off);
    }
    float ipZ = 1.f / Zp, iqZ = 1.f / Zq;

    // =============== JSD ===============
    // kl_pm + kl_qm = sum p log p + sum q log q - sum (p+q) log((p+q)/2 + eps)
    float cross = 0.f;
#pragma unroll
    for (int j = 0; j < 32; ++j) {
        float p = lp[j] * ipZ, q = lq[j] * iqZ;
        lp[j] = p; lq[j] = q;               // now hold soft weights
        float s = p + q;
        cross += s * __logf(0.5f * s + 1e-12f);
    }
#pragma unroll
    for (int off = 32; off; off >>= 1) cross += __shfl_xor(cross, off);
    if (lane == 0) {
        float Sp = Tp * ipZ - __logf(Zp);
        float Sq = Tq * iqZ - __logf(Zq);
        atomicAdd(Out + JSD_IDX, (Sp + Sq - cross) * (0.5f / 32768.f));
    }

    // =============== GEMM2: Zq = soft @ C_k ===============
    float4 ap4[12], aq4[12];
#pragma unroll
    for (int c4 = 0; c4 < 12; ++c4) {
        ap4[c4] = make_float4(0.f, 0.f, 0.f, 0.f);
        aq4[c4] = make_float4(0.f, 0.f, 0.f, 0.f);
    }
#pragma unroll
    for (int t = 0; t < 16; ++t) {
        __syncthreads();
#pragma unroll
        for (int i = 0; i < 6; ++i) {
            int idx = tid + i * 256;
            int mm  = idx / 12;
            int c4  = idx - mm * 12;
            CtT[c4][mm] = Cg4[(t * 128 + mm) * 96 + k * 12 + c4];
        }
        __syncthreads();
#pragma unroll
        for (int jj = 0; jj < 2; ++jj) {
            int   mloc = (jj << 6) + lane;
            float sp = lp[t * 2 + jj], sq = lq[t * 2 + jj];
#pragma unroll
            for (int c4 = 0; c4 < 12; ++c4) {
                float4 cv = CtT[c4][mloc];
                ap4[c4].x += sp * cv.x; ap4[c4].y += sp * cv.y;
                ap4[c4].z += sp * cv.z; ap4[c4].w += sp * cv.w;
                aq4[c4].x += sq * cv.x; aq4[c4].y += sq * cv.y;
                aq4[c4].z += sq * cv.z; aq4[c4].w += sq * cv.w;
            }
        }
    }
    // cross-lane reduce the 48-dim accumulators (all 64 lanes -> total)
#pragma unroll
    for (int off = 32; off; off >>= 1) {
#pragma unroll
        for (int c4 = 0; c4 < 12; ++c4) { RED4(ap4[c4]); RED4(aq4[c4]); }
    }
    if (lane == 0) {
#pragma unroll
        for (int c4 = 0; c4 < 12; ++c4) {
            zq4[wv][c4]     = ap4[c4];
            zq4[4 + wv][c4] = aq4[c4];
        }
    }
    __syncthreads();

    // ---- store: out[b,(k*48+c),pos] (384 items, strided loop) ----
    for (int i = tid; i < 384; i += 256) {
        int rr = i & 7;          // row in zq4
        int c  = i >> 3;         // 0..47
        int n  = r0 + (rr & 3) + ((rr & 4) ? 4096 : 0);
        int b  = n >> 10, pos = n & 1023;
        Out[b * Z_BCH + (k * 48 + c) * 1024 + pos] = ((const float*)zq4)[rr * 48 + c];
    }
}

extern "C" void kernel_launch(void* const* d_in, const int* in_sizes, int n_in,
                              void* d_out, int out_size, void* d_ws, size_t ws_size,
                              hipStream_t stream)
{
    const float* z = (const float*)d_in[0];
    const float* C = (const float*)d_in[1];
    float* out = (float*)d_out;

    // zero the jsd accumulator slot (captured as a memset node)
    hipMemsetAsync(out + JSD_IDX, 0, sizeof(float), stream);

    // 1024 pair-blocks * 8 subspaces; 4 waves/block, 1 (pair,k) per wave
    pq_fused<<<dim3(8192), dim3(256), 0, stream>>>(z, C, out);
}

// Round 3
// 1875.967 us; speedup vs baseline: 4.4161x; 4.4161x over previous
//
#include <hip/hip_runtime.h>

// Soft product quantizer.
// z: (8,384,32,32) f32, C: (2048,384) f32, it unused.
// N=8192 points (n = b*1024 + h*32 + w), K=8 subspaces, d=48, M=2048 codes.
// logits[n,k,m] = 2*<x_nk, c_mk> - ||c_mk||^2  (softmax-equivalent to -dist;
// the x^2 term is row-constant and cancels in softmax).
// soft = softmax(logits, m); Zq = soft @ C_k; JSD between rows n and n+4096.
// Output: 3145728 f32 (z_quantized, NCHW) + 1 f32 (jsd scalar).
//
// Round 3: fix scratch-spill catastrophe (R2: 12.8GB WRITE_SIZE = spills).
//  - __launch_bounds__(256,1): VGPR cap 512, live set ~190 -> no spill.
//  - c2 inlined into the dot loop (c2t array + 1 barrier/tile removed).
//  - staging map (mm = idx&127, c4 = idx>>7): conflict-free LDS writes.

#define Z_BCH  (384 * 1024)
#define JSD_IDX 3145728

#define RED4(v)                                   \
    v.x += __shfl_xor(v.x, off);                  \
    v.y += __shfl_xor(v.y, off);                  \
    v.z += __shfl_xor(v.z, off);                  \
    v.w += __shfl_xor(v.w, off);

__global__ __launch_bounds__(256, 1)
void pq_fused(const float* __restrict__ Zin, const float* __restrict__ Cb,
              float* __restrict__ Out)
{
    const int tid  = threadIdx.x;
    const int lane = tid & 63;
    const int wv   = tid >> 6;           // wave 0..3, one pair per wave
    const int pb   = blockIdx.x & 1023;  // 1024 pair-blocks (4 pairs each)
    const int k    = blockIdx.x >> 10;   // subspace 0..7
    const int r0   = pb << 2;            // first p-row of this block

    // C tile transposed: CtT[c4][m]. Row stride 129 f4: compute reads are
    // lane-consecutive m (conflict-free b128); staging writes (constant c4
    // per wave, consecutive m) are also conflict-free.
    __shared__ float4 CtT[12][129];
    __shared__ float4 xs4[8][12];  // 8 rows (4 p + 4 q) x 48 floats
    __shared__ float4 zq4[8][12];  // reduced Zq rows for the final store

    // ---- stage x rows (384 items, 256 threads, strided) ----
    for (int i = tid; i < 384; i += 256) {
        int row = i / 48;
        int c   = i - row * 48;
        int n   = r0 + (row & 3) + ((row & 4) ? 4096 : 0);
        int b   = n >> 10, pos = n & 1023;
        ((float*)xs4)[row * 48 + c] = Zin[b * Z_BCH + (k * 48 + c) * 1024 + pos];
    }
    __syncthreads();

    // x for this wave's pair -> registers.
    float4 xp[12], xq[12];
#pragma unroll
    for (int c4 = 0; c4 < 12; ++c4) { xp[c4] = xs4[wv][c4]; xq[c4] = xs4[4 + wv][c4]; }

    // Full logits in registers: m = j*64 + lane.
    float lp[32], lq[32];
    const float4* Cg4 = (const float4*)Cb;  // C row = 96 float4

    // =============== pass 1: logits (dist dot + inline c2) ===============
#pragma unroll 1
    for (int t = 0; t < 16; ++t) {
        __syncthreads();
#pragma unroll
        for (int i = 0; i < 6; ++i) {
            int idx = tid + i * 256;           // 1536 float4 per tile
            int mm  = idx & 127;
            int c4  = idx >> 7;
            CtT[c4][mm] = Cg4[(t * 128 + mm) * 96 + k * 12 + c4];
        }
        __syncthreads();
#pragma unroll
        for (int jj = 0; jj < 2; ++jj) {
            int   mloc = (jj << 6) + lane;
            float ap = 0.f, aq = 0.f, cc = 0.f;
#pragma unroll
            for (int c4 = 0; c4 < 12; ++c4) {
                float4 cv = CtT[c4][mloc];
                ap += cv.x * xp[c4].x; ap += cv.y * xp[c4].y;
                ap += cv.z * xp[c4].z; ap += cv.w * xp[c4].w;
                aq += cv.x * xq[c4].x; aq += cv.y * xq[c4].y;
                aq += cv.z * xq[c4].z; aq += cv.w * xq[c4].w;
                cc += cv.x * cv.x + cv.y * cv.y + cv.z * cv.z + cv.w * cv.w;
            }
            lp[t * 2 + jj] = 2.f * ap - cc;
            lq[t * 2 + jj] = 2.f * aq - cc;
        }
    }

    // =============== softmax (exact, in-wave) ===============
    float Mp = lp[0], Mq = lq[0];
#pragma unroll
    for (int j = 1; j < 32; ++j) { Mp = fmaxf(Mp, lp[j]); Mq = fmaxf(Mq, lq[j]); }
#pragma unroll
    for (int off = 32; off; off >>= 1) {
        Mp = fmaxf(Mp, __shfl_xor(Mp, off));
        Mq = fmaxf(Mq, __shfl_xor(Mq, off));
    }
    float Zp = 0.f, Zq = 0.f, Tp = 0.f, Tq = 0.f;
#pragma unroll
    for (int j = 0; j < 32; ++j) {
        float sp = lp[j] - Mp, sq = lq[j] - Mq;
        float ep = __expf(sp), eq = __expf(sq);
        Zp += ep; Zq += eq;
        Tp += ep * sp; Tq += eq * sq;   // for sum(p*log p) = T/Z - log Z
        lp[j] = ep; lq[j] = eq;
    }
#pragma unroll
    for (int off = 32; off; off >>= 1) {
        Zp += __shfl_xor(Zp, off); Zq += __shfl_xor(Zq, off);
        Tp += __shfl_xor(Tp, off); Tq += __shfl_xor(Tq, off);
    }
    float ipZ = 1.f / Zp, iqZ = 1.f / Zq;

    // =============== JSD ===============
    // kl_pm + kl_qm = sum p log p + sum q log q - sum (p+q) log((p+q)/2 + eps)
    float cross = 0.f;
#pragma unroll
    for (int j = 0; j < 32; ++j) {
        float p = lp[j] * ipZ, q = lq[j] * iqZ;
        lp[j] = p; lq[j] = q;               // now hold soft weights
        float s = p + q;
        cross += s * __logf(0.5f * s + 1e-12f);
    }
#pragma unroll
    for (int off = 32; off; off >>= 1) cross += __shfl_xor(cross, off);
    if (lane == 0) {
        float Sp = Tp * ipZ - __logf(Zp);
        float Sq = Tq * iqZ - __logf(Zq);
        atomicAdd(Out + JSD_IDX, (Sp + Sq - cross) * (0.5f / 32768.f));
    }

    // =============== pass 2: Zq = soft @ C_k ===============
    float4 ap4[12], aq4[12];
#pragma unroll
    for (int c4 = 0; c4 < 12; ++c4) {
        ap4[c4] = make_float4(0.f, 0.f, 0.f, 0.f);
        aq4[c4] = make_float4(0.f, 0.f, 0.f, 0.f);
    }
#pragma unroll 1
    for (int t = 0; t < 16; ++t) {
        __syncthreads();
#pragma unroll
        for (int i = 0; i < 6; ++i) {
            int idx = tid + i * 256;
            int mm  = idx & 127;
            int c4  = idx >> 7;
            CtT[c4][mm] = Cg4[(t * 128 + mm) * 96 + k * 12 + c4];
        }
        __syncthreads();
#pragma unroll
        for (int jj = 0; jj < 2; ++jj) {
            int   mloc = (jj << 6) + lane;
            float sp = lp[t * 2 + jj], sq = lq[t * 2 + jj];
#pragma unroll
            for (int c4 = 0; c4 < 12; ++c4) {
                float4 cv = CtT[c4][mloc];
                ap4[c4].x += sp * cv.x; ap4[c4].y += sp * cv.y;
                ap4[c4].z += sp * cv.z; ap4[c4].w += sp * cv.w;
                aq4[c4].x += sq * cv.x; aq4[c4].y += sq * cv.y;
                aq4[c4].z += sq * cv.z; aq4[c4].w += sq * cv.w;
            }
        }
    }
    // cross-lane reduce the 48-dim accumulators
#pragma unroll
    for (int off = 32; off; off >>= 1) {
#pragma unroll
        for (int c4 = 0; c4 < 12; ++c4) { RED4(ap4[c4]); RED4(aq4[c4]); }
    }
    if (lane == 0) {
#pragma unroll
        for (int c4 = 0; c4 < 12; ++c4) {
            zq4[wv][c4]     = ap4[c4];
            zq4[4 + wv][c4] = aq4[c4];
        }
    }
    __syncthreads();

    // ---- store: out[b,(k*48+c),pos] (384 items, strided) ----
    for (int i = tid; i < 384; i += 256) {
        int rr = i & 7;          // row in zq4
        int c  = i >> 3;         // 0..47
        int n  = r0 + (rr & 3) + ((rr & 4) ? 4096 : 0);
        int b  = n >> 10, pos = n & 1023;
        Out[b * Z_BCH + (k * 48 + c) * 1024 + pos] = ((const float*)zq4)[rr * 48 + c];
    }
}

extern "C" void kernel_launch(void* const* d_in, const int* in_sizes, int n_in,
                              void* d_out, int out_size, void* d_ws, size_t ws_size,
                              hipStream_t stream)
{
    const float* z = (const float*)d_in[0];
    const float* C = (const float*)d_in[1];
    float* out = (float*)d_out;

    // zero the jsd accumulator slot (captured as a memset node)
    hipMemsetAsync(out + JSD_IDX, 0, sizeof(float), stream);

    // 1024 pair-blocks * 8 subspaces; 4 waves/block, 1 (pair,k) per wave
    pq_fused<<<dim3(8192), dim3(256), 0, stream>>>(z, C, out);
}

// Round 8
// 950.650 us; speedup vs baseline: 8.7146x; 1.9734x over previous
//
#include <hip/hip_runtime.h>

// Soft product quantizer — pure-f32 VALU "quad" kernel.
// z:(8,384,32,32) f32, C:(2048,384) f32. 4096 pairs (n, n+4096) x K=8, d=48, M=2048.
// s = 2<x,c> - |c|^2 (x^2 cancels in softmax; |s| small -> no max-subtract).
// Pass A (online): Z = sum e^s, T = sum e^s*s, O = sum e^s * c  -> O*(1/Z) at store.
// Pass B: recompute dots -> JSD cross term sum (p+q)*log((p+q)/2 + eps).
// jsd = [sum_rows (T/Z - log Z) - sum_pairs cross] * 0.5 / 32768.
//
// Layout: lane&15 = pair-in-wave, lane>>4 = dim-quarter (12 dims). 4 lanes/pair.
// Block = 4 waves = 64 pairs, one k. Grid = 64 pair-groups x 8 k = 512 blocks
// (exactly 2 blocks/CU, 2 waves/SIMD). C tiles (64 codes) double-buffered in
// LDS; all compute-side LDS reads are 4-address broadcasts (conflict-free).

#define Z_BCH   (384*1024)
#define JSD_IDX 3145728

__global__ __launch_bounds__(256, 2)
void pq_valu2(const float* __restrict__ Zin, const float* __restrict__ Cb,
              float* __restrict__ Out)
{
    __shared__ float cbuf[2][64][48];   // 24 KB
    __shared__ float c2p[2][64][4];     // per-quarter |c|^2 partials
    __shared__ float jred[4];

    const int tid  = threadIdx.x;
    const int lane = tid & 63;
    const int wv   = tid >> 6;
    const int pr   = lane & 15;         // pair within wave
    const int dqi  = lane >> 4;         // dim quarter 0..3
    const int pg   = blockIdx.x & 63;   // pair-group
    const int k    = blockIdx.x >> 6;   // subspace

    const int pairIdx = pg*64 + wv*16 + pr;          // 0..4095
    const int np = pairIdx, nq = pairIdx + 4096;
    const size_t basep = (size_t)(np >> 10)*Z_BCH + (np & 1023);
    const size_t baseq = (size_t)(nq >> 10)*Z_BCH + (nq & 1023);
    const int ch0 = k*48 + dqi*12;

    // x fragments (pre-doubled: logit = sum c*(2x) - c2)
    float x2p[12], x2q[12];
#pragma unroll
    for (int i = 0; i < 12; ++i) {
        x2p[i] = 2.f * Zin[basep + (size_t)(ch0 + i)*1024];
        x2q[i] = 2.f * Zin[baseq + (size_t)(ch0 + i)*1024];
    }

    // staging role: thread stages 12 dims (quarter p8) of code sm
    const int sm = tid & 63, p8 = tid >> 6;
    float4 sa, sb, sc;

#define SLOAD(m0) do {                                                        \
        const float* _p = Cb + (size_t)((m0) + sm)*384 + k*48 + p8*12;        \
        sa = *(const float4*)(_p);                                            \
        sb = *(const float4*)(_p + 4);                                        \
        sc = *(const float4*)(_p + 8);                                        \
    } while (0)

#define SWRITE(b) do {                                                        \
        *(float4*)&cbuf[b][sm][p8*12]     = sa;                               \
        *(float4*)&cbuf[b][sm][p8*12 + 4] = sb;                               \
        *(float4*)&cbuf[b][sm][p8*12 + 8] = sc;                               \
        c2p[b][sm][p8] = sa.x*sa.x + sa.y*sa.y + sa.z*sa.z + sa.w*sa.w        \
                       + sb.x*sb.x + sb.y*sb.y + sb.z*sb.z + sb.w*sb.w        \
                       + sc.x*sc.x + sc.y*sc.y + sc.z*sc.z + sc.w*sc.w;       \
    } while (0)

#define LOADCV(b, m)                                                          \
        float cvf[12];                                                        \
        *(float4*)&cvf[0] = *(const float4*)&cbuf[b][m][dqi*12];              \
        *(float4*)&cvf[4] = *(const float4*)&cbuf[b][m][dqi*12 + 4];          \
        *(float4*)&cvf[8] = *(const float4*)&cbuf[b][m][dqi*12 + 8];          \
        const float c2q_ = c2p[b][m][dqi];

#define DOTS()                                                                \
        float dpe = 0.f, dpo = 0.f, dqe = 0.f, dqo = 0.f;                     \
        _Pragma("unroll")                                                     \
        for (int i = 0; i < 12; i += 2) {                                     \
            dpe = fmaf(cvf[i],   x2p[i],   dpe);                              \
            dpo = fmaf(cvf[i+1], x2p[i+1], dpo);                              \
            dqe = fmaf(cvf[i],   x2q[i],   dqe);                              \
            dqo = fmaf(cvf[i+1], x2q[i+1], dqo);                              \
        }                                                                     \
        float sp = dpe + dpo - c2q_;                                          \
        float sq = dqe + dqo - c2q_;                                          \
        sp += __shfl_xor(sp, 16); sp += __shfl_xor(sp, 32);                   \
        sq += __shfl_xor(sq, 16); sq += __shfl_xor(sq, 32);

    // =================== pass A: stats + un-normalized O ===================
    float Zp = 0.f, Tp = 0.f, Zq = 0.f, Tq = 0.f;
    float Op[12], Oq[12];
#pragma unroll
    for (int i = 0; i < 12; ++i) { Op[i] = 0.f; Oq[i] = 0.f; }

    SLOAD(0); SWRITE(0);
    __syncthreads();
    int buf = 0;
#pragma unroll 1
    for (int t = 0; t < 32; ++t) {
        if (t < 31) SLOAD((t + 1)*64);
#pragma unroll 2
        for (int m = 0; m < 64; ++m) {
            LOADCV(buf, m);
            DOTS();
            float ep = __expf(sp), eq = __expf(sq);
            Zp += ep; Tp = fmaf(ep, sp, Tp);
            Zq += eq; Tq = fmaf(eq, sq, Tq);
#pragma unroll
            for (int i = 0; i < 12; ++i) {
                Op[i] = fmaf(ep, cvf[i], Op[i]);
                Oq[i] = fmaf(eq, cvf[i], Oq[i]);
            }
        }
        if (t < 31) SWRITE(buf ^ 1);
        __syncthreads();
        buf ^= 1;
    }

    const float izp = 1.f / Zp, izq = 1.f / Zq;
    const float entp = Tp*izp - __logf(Zp);   // sum p log p
    const float entq = Tq*izq - __logf(Zq);

    // =================== pass B: JSD cross term ===================
    float cross = 0.f;
    SLOAD(0); SWRITE(0);
    __syncthreads();
    buf = 0;
#pragma unroll 1
    for (int t = 0; t < 32; ++t) {
        if (t < 31) SLOAD((t + 1)*64);
#pragma unroll 2
        for (int m = 0; m < 64; ++m) {
            LOADCV(buf, m);
            DOTS();
            float ep = __expf(sp), eq = __expf(sq);
            float s = fmaf(ep, izp, eq*izq);           // p + q
            cross = fmaf(s, __logf(fmaf(0.5f, s, 1e-12f)), cross);
        }
        if (t < 31) SWRITE(buf ^ 1);
        __syncthreads();
        buf ^= 1;
    }

    // =================== JSD reduce (each pair counted 4x) ===================
    float jloc = entp + entq - cross;
#pragma unroll
    for (int off = 1; off < 64; off <<= 1) jloc += __shfl_xor(jloc, off);
    if (lane == 0) jred[wv] = jloc;
    __syncthreads();
    if (tid == 0)
        atomicAdd(Out + JSD_IDX,
                  (jred[0] + jred[1] + jred[2] + jred[3]) * (0.5f / (32768.f * 4.f)));

    // =================== store O (normalized) ===================
#pragma unroll
    for (int i = 0; i < 12; ++i) {
        Out[basep + (size_t)(ch0 + i)*1024] = Op[i]*izp;
        Out[baseq + (size_t)(ch0 + i)*1024] = Oq[i]*izq;
    }
}

extern "C" void kernel_launch(void* const* d_in, const int* in_sizes, int n_in,
                              void* d_out, int out_size, void* d_ws, size_t ws_size,
                              hipStream_t stream)
{
    const float* z = (const float*)d_in[0];
    const float* C = (const float*)d_in[1];
    float* out = (float*)d_out;

    hipMemsetAsync(out + JSD_IDX, 0, sizeof(float), stream);

    // 64 pair-groups (64 pairs each) x 8 subspaces = 512 blocks, 256 thr
    pq_valu2<<<dim3(512), dim3(256), 0, stream>>>(z, C, out);
}

// Round 9
// 768.866 us; speedup vs baseline: 10.7750x; 1.2364x over previous
//
#include <hip/hip_runtime.h>

// Soft product quantizer — pure-f32 VALU, 8-lanes-per-pair (occupancy round).
// z:(8,384,32,32) f32, C:(2048,384) f32. 4096 pairs (n, n+4096) x K=8, d=48, M=2048.
// s = 2<x,c> - |c|^2 (x^2 cancels in softmax; |s| small -> no max-subtract).
// Pass A (online): Z = sum e^s, T = sum e^s*s, O = sum e^s*c -> O*(1/Z) at store.
// Pass B: recompute dots -> cross = sum (p+q)*log((p+q)/2 + eps).
// jsd = sum_{pair,k} [entp + entq - cross] * 0.5 / 32768.
//
// Lane split: pr=lane&7 (pair), row=bit3 (p/q), ph=bit4 (dim half of 24),
// ch=bit5 (code parity). 8 pairs/wave -> 4096 waves -> 4 waves/SIMD.
// Block = 4 waves = 32 pairs, one k. Grid = 128 pair-groups x 8 k = 1024
// blocks (4 blocks/CU). C tiles (64 codes) double-buffered in LDS, stride 52
// (cols 48-51 = per-quarter |c|^2 partials). Compute LDS reads: 4 distinct
// broadcast addresses/issue, distinct bank quads (stride 52) -> conflict-free.

#define Z_BCH   (384*1024)
#define JSD_IDX 3145728

__global__ __launch_bounds__(256, 4)
void pq_valu3(const float* __restrict__ Zin, const float* __restrict__ Cb,
              float* __restrict__ Out)
{
    __shared__ float cbuf[2][64][52];   // 26.6 KB
    __shared__ float jred[4];

    const int tid  = threadIdx.x;
    const int lane = tid & 63;
    const int wv   = tid >> 6;
    const int pr   = lane & 7;          // pair within wave
    const int row  = (lane >> 3) & 1;   // 0 = p (n), 1 = q (n+4096)
    const int ph   = (lane >> 4) & 1;   // dim half (24 dims)
    const int ch   = lane >> 5;         // code parity
    const int pg   = blockIdx.x & 127;  // 128 pair-groups of 32
    const int k    = blockIdx.x >> 7;   // subspace

    const int pairIdx = pg*32 + wv*8 + pr;          // 0..4095
    const int n = pairIdx + row*4096;
    const size_t base = (size_t)(n >> 10)*Z_BCH + (n & 1023);
    const int d0 = ph*24;

    // x fragment (pre-doubled): s = sum c*(2x) - c2
    float x2[24];
#pragma unroll
    for (int i = 0; i < 24; ++i)
        x2[i] = 2.f * Zin[base + (size_t)(k*48 + d0 + i)*1024];

    // staging role: thread stages 12 dims (quarter p8) of code sm
    const int sm = tid & 63, p8 = tid >> 6;
    float4 sa, sb, sc;

#define SLOAD(m0) do {                                                        \
        const float* _p = Cb + (size_t)((m0) + sm)*384 + k*48 + p8*12;        \
        sa = *(const float4*)(_p);                                            \
        sb = *(const float4*)(_p + 4);                                        \
        sc = *(const float4*)(_p + 8);                                        \
    } while (0)

#define SWRITE(b) do {                                                        \
        *(float4*)&cbuf[b][sm][p8*12]     = sa;                               \
        *(float4*)&cbuf[b][sm][p8*12 + 4] = sb;                               \
        *(float4*)&cbuf[b][sm][p8*12 + 8] = sc;                               \
        cbuf[b][sm][48 + p8] = sa.x*sa.x + sa.y*sa.y + sa.z*sa.z + sa.w*sa.w  \
                             + sb.x*sb.x + sb.y*sb.y + sb.z*sb.z + sb.w*sb.w  \
                             + sc.x*sc.x + sc.y*sc.y + sc.z*sc.z + sc.w*sc.w; \
    } while (0)

#define LOADC(b, m)                                                           \
        float cvf[24];                                                        \
        *(float4*)&cvf[0]  = *(const float4*)&cbuf[b][m][d0];                 \
        *(float4*)&cvf[4]  = *(const float4*)&cbuf[b][m][d0 + 4];             \
        *(float4*)&cvf[8]  = *(const float4*)&cbuf[b][m][d0 + 8];             \
        *(float4*)&cvf[12] = *(const float4*)&cbuf[b][m][d0 + 12];            \
        *(float4*)&cvf[16] = *(const float4*)&cbuf[b][m][d0 + 16];            \
        *(float4*)&cvf[20] = *(const float4*)&cbuf[b][m][d0 + 20];            \
        float2 c2h = *(const float2*)&cbuf[b][m][48 + ph*2];

#define HDOT()                                                                \
        float a0 = 0.f, a1 = 0.f;                                             \
        _Pragma("unroll")                                                     \
        for (int i = 0; i < 24; i += 2) {                                     \
            a0 = fmaf(cvf[i],   x2[i],   a0);                                 \
            a1 = fmaf(cvf[i+1], x2[i+1], a1);                                 \
        }                                                                     \
        float sh = a0 + a1 - c2h.x - c2h.y;                                   \
        float s  = sh + __shfl_xor(sh, 16);   /* sum the two dim-halves */

    // =================== pass A: stats + un-normalized O ===================
    float Zs = 0.f, Ts = 0.f;
    float O[24];
#pragma unroll
    for (int i = 0; i < 24; ++i) O[i] = 0.f;

    SLOAD(0); SWRITE(0);
    __syncthreads();
    int buf = 0;
#pragma unroll 1
    for (int t = 0; t < 32; ++t) {
        if (t < 31) SLOAD((t + 1)*64);
#pragma unroll 4
        for (int mb = 0; mb < 32; ++mb) {
            int m = mb*2 + ch;
            LOADC(buf, m);
            HDOT();
            float e = __expf(s);
            Zs += e; Ts = fmaf(e, s, Ts);
#pragma unroll
            for (int i = 0; i < 24; ++i) O[i] = fmaf(e, cvf[i], O[i]);
        }
        if (t < 31) SWRITE(buf ^ 1);
        __syncthreads();
        buf ^= 1;
    }

    // combine the two code-parities (ph copies are bit-identical already)
    Zs += __shfl_xor(Zs, 32);
    Ts += __shfl_xor(Ts, 32);
    const float iz   = 1.f / Zs;
    const float entr = Ts*iz - __logf(Zs);   // sum p log p (own row)
#pragma unroll
    for (int i = 0; i < 24; ++i) O[i] += __shfl_xor(O[i], 32);

    // =================== pass B: JSD cross term ===================
    float cross = 0.f;
    SLOAD(0); SWRITE(0);
    __syncthreads();
    buf = 0;
#pragma unroll 1
    for (int t = 0; t < 32; ++t) {
        if (t < 31) SLOAD((t + 1)*64);
#pragma unroll 4
        for (int mb = 0; mb < 32; ++mb) {
            int m = mb*2 + ch;
            LOADC(buf, m);
            HDOT();
            float pown = __expf(s) * iz;
            float ssum = pown + __shfl_xor(pown, 8);   // p + q (row partner)
            cross = fmaf(ssum, __logf(fmaf(0.5f, ssum, 1e-12f)), cross);
        }
        if (t < 31) SWRITE(buf ^ 1);
        __syncthreads();
        buf ^= 1;
    }

    // =================== JSD reduce ===================
    // per pair: entr counted 4x (ph*ch), cross counted 4x (row*ph, ch-split)
    float jloc = entr - cross;
#pragma unroll
    for (int off = 1; off < 64; off <<= 1) jloc += __shfl_xor(jloc, off);
    if (lane == 0) jred[wv] = jloc;
    __syncthreads();
    if (tid == 0)
        atomicAdd(Out + JSD_IDX,
                  (jred[0] + jred[1] + jred[2] + jred[3]) * (0.25f * 0.5f / 32768.f));

    // =================== store O (normalized; ch splits the 24 dims) ===================
#pragma unroll
    for (int i = 0; i < 12; ++i)
        Out[base + (size_t)(k*48 + d0 + ch*12 + i)*1024] = O[ch*12 + i]*iz;
}

extern "C" void kernel_launch(void* const* d_in, const int* in_sizes, int n_in,
                              void* d_out, int out_size, void* d_ws, size_t ws_size,
                              hipStream_t stream)
{
    const float* z = (const float*)d_in[0];
    const float* C = (const float*)d_in[1];
    float* out = (float*)d_out;

    hipMemsetAsync(out + JSD_IDX, 0, sizeof(float), stream);

    // 128 pair-groups (32 pairs each) x 8 subspaces = 1024 blocks
    pq_valu3<<<dim3(1024), dim3(256), 0, stream>>>(z, C, out);
}

// Round 10
// 583.489 us; speedup vs baseline: 14.1983x; 1.3177x over previous
//
#include <hip/hip_runtime.h>

// Soft product quantizer — f16 dot2 kernel (v_dot2_f32_f16, f32 accumulate).
// z:(8,384,32,32) f32, C:(2048,384) f32. 4096 pairs (n, n+4096) x K=8, d=48, M=2048.
// s = 2<x,c> - |c|^2 (x^2 cancels in softmax; |s| small -> no max-subtract).
// Pass A (online): Z = sum e^s, T = sum e^s*s, O = sum e^s*c -> O*(1/Z) at store.
// Pass B: recompute s -> cross = sum (p+q)*log((p+q)/2 + eps).
// jsd = sum_{pair,k} [entp + entq - cross] * 0.5 / 32768.
//
// Lanes: pr=lane&7 (pair), row=bit3 (p/q), cs=lane>>4 (codes m = 4*mb+cs).
// Each lane: FULL 48-dim dot for its row/codes -> s lane-local, no in-loop shfl.
// x and C-tile in packed f16 (f32 accum): dot = 26 fdot2; O-update = 48 fdot2
// via (e,0)/(0,e) pairs. c2 folded as f16 partials at cols 48..51, x-side -1.
// Block = 4 waves = 32 pairs, one k; grid 128x8 = 1024 (4 blocks/CU). C tile
// 64 codes double-buffered, stride 56 f16 = 112B -> broadcast reads hit banks
// {0-3,28-31,24-27,20-23}: conflict-free.

typedef __fp16 f16;
typedef __attribute__((ext_vector_type(2))) __fp16 f16x2;

#define Z_BCH   (384*1024)
#define JSD_IDX 3145728

__device__ __forceinline__ f16x2 u2h(unsigned u) {
    union { unsigned u; f16x2 h; } c; c.u = u; return c.h;
}
__device__ __forceinline__ unsigned h2u(f16x2 h) {
    union { f16x2 h; unsigned u; } c; c.h = h; return c.u;
}
__device__ __forceinline__ float fdot2f(f16x2 a, f16x2 b, float c) {
#if __has_builtin(__builtin_amdgcn_fdot2)
    return __builtin_amdgcn_fdot2(a, b, c, false);
#else
    return fmaf((float)a.y, (float)b.y, fmaf((float)a.x, (float)b.x, c));
#endif
}

__global__ __launch_bounds__(256, 4)
void pq_dot2(const float* __restrict__ Zin, const float* __restrict__ Cb,
             float* __restrict__ Out)
{
    __shared__ __align__(16) unsigned short cbuf[2][64][56];  // f16 tile x2 (14.3 KB)
    __shared__ float jred[4];

    const int tid  = threadIdx.x;
    const int lane = tid & 63;
    const int wv   = tid >> 6;
    const int pr   = lane & 7;          // pair within wave
    const int row  = (lane >> 3) & 1;   // 0 = p (n), 1 = q (n+4096)
    const int cs   = lane >> 4;         // code class: m ≡ cs (mod 4)
    const int pg   = blockIdx.x & 127;  // 128 pair-groups of 32
    const int k    = blockIdx.x >> 7;   // subspace

    const int pairIdx = pg*32 + wv*8 + pr;          // 0..4095
    const int n = pairIdx + row*4096;
    const size_t base = (size_t)(n >> 10)*Z_BCH + (n & 1023);

    // x packed f16, pre-doubled: s = sum (2x)*c - |c|^2
    f16x2 x2[26];
#pragma unroll
    for (int j = 0; j < 24; ++j) {
        float a = 2.f * Zin[base + (size_t)(k*48 + 2*j    )*1024];
        float b = 2.f * Zin[base + (size_t)(k*48 + 2*j + 1)*1024];
        x2[j] = __builtin_amdgcn_cvt_pkrtz(a, b);
    }
    x2[24] = __builtin_amdgcn_cvt_pkrtz(-1.f, -1.f);   // c2 partial pads
    x2[25] = x2[24];

    // staging: thread = (code sm, dim-quarter p8); f32 -> f16 on the fly
    const int sm = tid & 63, p8 = tid >> 6;
    unsigned w0, w1, w2, w3, w4, w5; unsigned short wc2;

#define SLOAD(m0) do {                                                        \
        const float* _p = Cb + (size_t)((m0) + sm)*384 + k*48 + p8*12;        \
        float4 va = *(const float4*)(_p);                                     \
        float4 vb = *(const float4*)(_p + 4);                                 \
        float4 vc = *(const float4*)(_p + 8);                                 \
        w0 = h2u(__builtin_amdgcn_cvt_pkrtz(va.x, va.y));                     \
        w1 = h2u(__builtin_amdgcn_cvt_pkrtz(va.z, va.w));                     \
        w2 = h2u(__builtin_amdgcn_cvt_pkrtz(vb.x, vb.y));                     \
        w3 = h2u(__builtin_amdgcn_cvt_pkrtz(vb.z, vb.w));                     \
        w4 = h2u(__builtin_amdgcn_cvt_pkrtz(vc.x, vc.y));                     \
        w5 = h2u(__builtin_amdgcn_cvt_pkrtz(vc.z, vc.w));                     \
        float c2 = va.x*va.x + va.y*va.y + va.z*va.z + va.w*va.w              \
                 + vb.x*vb.x + vb.y*vb.y + vb.z*vb.z + vb.w*vb.w              \
                 + vc.x*vc.x + vc.y*vc.y + vc.z*vc.z + vc.w*vc.w;             \
        wc2 = (unsigned short)(h2u(__builtin_amdgcn_cvt_pkrtz(c2, 0.f)) & 0xFFFF); \
    } while (0)

#define SWRITE(b) do {                                                        \
        *(uint2*)&cbuf[b][sm][p8*12    ] = make_uint2(w0, w1);                \
        *(uint2*)&cbuf[b][sm][p8*12 + 4] = make_uint2(w2, w3);                \
        *(uint2*)&cbuf[b][sm][p8*12 + 8] = make_uint2(w4, w5);                \
        cbuf[b][sm][48 + p8] = wc2;                                           \
    } while (0)

    // load one code row (f16) + dot against x2 -> s (f32)
#define LOADDOT(b, m)                                                         \
    unsigned cw[24];                                                          \
    {   uint4 q0 = *(const uint4*)&cbuf[b][m][0];                             \
        uint4 q1 = *(const uint4*)&cbuf[b][m][8];                             \
        uint4 q2 = *(const uint4*)&cbuf[b][m][16];                            \
        uint4 q3 = *(const uint4*)&cbuf[b][m][24];                            \
        uint4 q4 = *(const uint4*)&cbuf[b][m][32];                            \
        uint4 q5 = *(const uint4*)&cbuf[b][m][40];                            \
        cw[0]=q0.x;  cw[1]=q0.y;  cw[2]=q0.z;  cw[3]=q0.w;                    \
        cw[4]=q1.x;  cw[5]=q1.y;  cw[6]=q1.z;  cw[7]=q1.w;                    \
        cw[8]=q2.x;  cw[9]=q2.y;  cw[10]=q2.z; cw[11]=q2.w;                   \
        cw[12]=q3.x; cw[13]=q3.y; cw[14]=q3.z; cw[15]=q3.w;                   \
        cw[16]=q4.x; cw[17]=q4.y; cw[18]=q4.z; cw[19]=q4.w;                   \
        cw[20]=q5.x; cw[21]=q5.y; cw[22]=q5.z; cw[23]=q5.w;                   \
    }                                                                         \
    uint2 c2w = *(const uint2*)&cbuf[b][m][48];                               \
    float sA = 0.f, sB = 0.f;                                                 \
    _Pragma("unroll")                                                         \
    for (int j = 0; j < 24; j += 2) {                                         \
        sA = fdot2f(u2h(cw[j]),   x2[j],   sA);                               \
        sB = fdot2f(u2h(cw[j+1]), x2[j+1], sB);                               \
    }                                                                         \
    sA = fdot2f(u2h(c2w.x), x2[24], sA);                                      \
    sB = fdot2f(u2h(c2w.y), x2[25], sB);                                      \
    float s = sA + sB;

    // =================== pass A: stats + un-normalized O ===================
    float Zs = 0.f, Ts = 0.f;
    float O[48];
#pragma unroll
    for (int i = 0; i < 48; ++i) O[i] = 0.f;

    SLOAD(0); SWRITE(0);
    __syncthreads();
    int buf = 0;
#pragma unroll 1
    for (int t = 0; t < 32; ++t) {
        if (t < 31) SLOAD((t + 1)*64);
#pragma unroll 4
        for (int mb = 0; mb < 16; ++mb) {
            const int m = mb*4 + cs;
            LOADDOT(buf, m);
            float e = __expf(s);
            Zs += e; Ts = fmaf(e, s, Ts);
            f16x2 ea = __builtin_amdgcn_cvt_pkrtz(e, 0.f);
            f16x2 eb = __builtin_amdgcn_cvt_pkrtz(0.f, e);
#pragma unroll
            for (int j = 0; j < 24; ++j) {
                O[2*j]   = fdot2f(u2h(cw[j]), ea, O[2*j]);
                O[2*j+1] = fdot2f(u2h(cw[j]), eb, O[2*j+1]);
            }
        }
        if (t < 31) SWRITE(buf ^ 1);
        __syncthreads();
        buf ^= 1;
    }

    // reduce Z,T over the 4 code-classes (lane bits 4,5)
    Zs += __shfl_xor(Zs, 16); Zs += __shfl_xor(Zs, 32);
    Ts += __shfl_xor(Ts, 16); Ts += __shfl_xor(Ts, 32);
    const float iz   = 1.f / Zs;
    const float entr = Ts*iz - __logf(Zs);   // sum p log p (own row)

    // =================== pass B: JSD cross term ===================
    float cross = 0.f;
    SLOAD(0); SWRITE(0);
    __syncthreads();
    buf = 0;
#pragma unroll 1
    for (int t = 0; t < 32; ++t) {
        if (t < 31) SLOAD((t + 1)*64);
#pragma unroll 4
        for (int mb = 0; mb < 16; ++mb) {
            const int m = mb*4 + cs;
            LOADDOT(buf, m);
            float pown = __expf(s) * iz;
            float ssum = pown + __shfl_xor(pown, 8);    // p + q (row partner)
            cross = fmaf(ssum, __logf(fmaf(0.5f, ssum, 1e-12f)), cross);
        }
        if (t < 31) SWRITE(buf ^ 1);
        __syncthreads();
        buf ^= 1;
    }

    // =================== JSD reduce ===================
    // per pair: entr appears 4x per row (cs), cross appears 2x per m (rows)
    float jloc = 0.25f*entr - 0.5f*cross;
#pragma unroll
    for (int off = 1; off < 64; off <<= 1) jloc += __shfl_xor(jloc, off);
    if (lane == 0) jred[wv] = jloc;
    __syncthreads();
    if (tid == 0)
        atomicAdd(Out + JSD_IDX,
                  (jred[0] + jred[1] + jred[2] + jred[3]) * (0.5f / 32768.f));

    // =================== store O (reduce over cs, normalize) ===================
#pragma unroll
    for (int i = 0; i < 48; ++i) {
        O[i] += __shfl_xor(O[i], 16);
        O[i] += __shfl_xor(O[i], 32);
    }
#define STORE12(c0)                                                           \
    { _Pragma("unroll")                                                       \
      for (int j = 0; j < 12; ++j)                                            \
          Out[base + (size_t)(k*48 + (c0) + j)*1024] = O[(c0) + j]*iz; }
    if      (cs == 0) STORE12(0)
    else if (cs == 1) STORE12(12)
    else if (cs == 2) STORE12(24)
    else              STORE12(36)
}

extern "C" void kernel_launch(void* const* d_in, const int* in_sizes, int n_in,
                              void* d_out, int out_size, void* d_ws, size_t ws_size,
                              hipStream_t stream)
{
    const float* z = (const float*)d_in[0];
    const float* C = (const float*)d_in[1];
    float* out = (float*)d_out;

    hipMemsetAsync(out + JSD_IDX, 0, sizeof(float), stream);

    // 128 pair-groups (32 pairs each) x 8 subspaces = 1024 blocks
    pq_dot2<<<dim3(1024), dim3(256), 0, stream>>>(z, C, out);
}